// Round 10
// baseline (26451.657 us; speedup 1.0000x reference)
//
#include <hip/hip_runtime.h>
#include <math.h>

#define A_PL 22
#define F_IN_ 16
#define T_LEN 256

__device__ __forceinline__ float sigmoidf_(float x) { return 1.f / (1.f + __expf(-x)); }

// seq_lengths: int64 or int32. True values in [128,256], never 0 =>
// little-endian int64 has lens32[1]==0.
__device__ __forceinline__ int read_len(const int* __restrict__ lens, int b) {
  return (lens[1] == 0) ? lens[2 * b] : lens[b];
}

// ---------------------------------------------------------------------------
// Kernel 1: NAIVE fused GAT (proven correct in R8 — untouched this round).
// ---------------------------------------------------------------------------
__global__ __launch_bounds__(256) void gat_naive(
    const float* __restrict__ feat, const int* __restrict__ lens,
    const float* __restrict__ W1, const float* __restrict__ as1,
    const float* __restrict__ ad1, const float* __restrict__ b1,
    const float* __restrict__ W2, const float* __restrict__ as2,
    const float* __restrict__ ad2, const float* __restrict__ b2,
    float* __restrict__ pooled)
{
  const int n = blockIdx.x;
  const int tid = threadIdx.x;
  const int bb = n >> 8;          // batch
  const int tt = n & 255;         // time
  if (tt >= read_len(lens, bb)) { // masked frame: pooled = 0
    if (tid < 128) pooled[(size_t)n * 128 + tid] = 0.f;
    return;
  }

  __shared__ float xs[352];       // x [22][16]
  __shared__ float hbuf[2816];    // per-head h [22][128]; later h2 [22][128]
  __shared__ float x2s[11264];    // GAT1 output [22][512] (relu'd)
  __shared__ float asrc[22], adst[22], alpha[484];

  for (int i = tid; i < 352; i += 256) xs[i] = feat[(size_t)n * 352 + i];
  __syncthreads();

  for (int hd = 0; hd < 4; hd++) {
    for (int i = tid; i < 2816; i += 256) {
      int a = i >> 7, c = i & 127;
      float acc = 0.f;
      for (int f = 0; f < 16; f++) acc += xs[a * 16 + f] * W1[f * 512 + hd * 128 + c];
      hbuf[i] = acc;
    }
    __syncthreads();
    if (tid < 44) {
      int a = tid >> 1;
      const float* av = (tid & 1) ? ad1 : as1;
      float s = 0.f;
      for (int c = 0; c < 128; c++) s += hbuf[a * 128 + c] * av[hd * 128 + c];
      ((tid & 1) ? adst : asrc)[a] = s;
    }
    __syncthreads();
    if (tid < 22) {
      float ev[22], m = -1e30f;
      for (int j = 0; j < 22; j++) {
        float e = adst[tid] + asrc[j];
        e = (e > 0.f) ? e : 0.2f * e;
        ev[j] = e; if (e > m) m = e;
      }
      float s = 0.f;
      for (int j = 0; j < 22; j++) { ev[j] = __expf(ev[j] - m); s += ev[j]; }
      float inv = 1.f / s;
      for (int j = 0; j < 22; j++) alpha[tid * 22 + j] = ev[j] * inv;
    }
    __syncthreads();
    for (int i = tid; i < 2816; i += 256) {
      int a = i >> 7, c = i & 127;
      float acc = 0.f;
      for (int j = 0; j < 22; j++) acc += alpha[a * 22 + j] * hbuf[j * 128 + c];
      x2s[a * 512 + hd * 128 + c] = fmaxf(acc + b1[hd * 128 + c], 0.f);
    }
    __syncthreads();
  }

  for (int i = tid; i < 2816; i += 256) {
    int a = i >> 7, c = i & 127;
    float acc = 0.f;
    for (int k = 0; k < 512; k++) acc += x2s[a * 512 + k] * W2[(size_t)k * 128 + c];
    hbuf[i] = acc;
  }
  __syncthreads();
  if (tid < 44) {
    int a = tid >> 1;
    const float* av = (tid & 1) ? ad2 : as2;
    float s = 0.f;
    for (int c = 0; c < 128; c++) s += hbuf[a * 128 + c] * av[c];
    ((tid & 1) ? adst : asrc)[a] = s;
  }
  __syncthreads();
  if (tid < 22) {
    float ev[22], m = -1e30f;
    for (int j = 0; j < 22; j++) {
      float e = adst[tid] + asrc[j];
      e = (e > 0.f) ? e : 0.2f * e;
      ev[j] = e; if (e > m) m = e;
    }
    float s = 0.f;
    for (int j = 0; j < 22; j++) { ev[j] = __expf(ev[j] - m); s += ev[j]; }
    float inv = 1.f / s;
    for (int j = 0; j < 22; j++) alpha[tid * 22 + j] = ev[j] * inv;
  }
  __syncthreads();
  if (tid < 128) {
    float s = 0.f;
    for (int a = 0; a < 22; a++) {
      float v = b2[tid];
      for (int j = 0; j < 22; j++) v += alpha[a * 22 + j] * hbuf[j * 128 + tid];
      s += fmaxf(v, 0.f);
    }
    pooled[(size_t)n * 128 + tid] = s * (1.f / 22.f);
  }
}

// ---------------------------------------------------------------------------
// Kernel 2: big-block LSTM. One 1024-thread block per batch element (32
// blocks, 16 waves/block). Thread tid owns gate-row tid (PyTorch layout:
// rows [0,256)=i, [256,512)=f, [512,768)=g, [768,1024)=o). All recurrent
// state in LDS; 4 __syncthreads per step; NO grid-wide sync (grid.sync
// measured ~30us on this platform -> 16ms for 512 phases in R9).
// Weight rows re-read each step stay L2-resident (3.5MB < 4MB XCD L2).
// ---------------------------------------------------------------------------
__global__ __launch_bounds__(1024) void lstm_big(
    const float* __restrict__ pooled,
    const float* __restrict__ Wih0, const float* __restrict__ bih0,
    const float* __restrict__ bhh0, const float* __restrict__ Whh0,
    const float* __restrict__ Wih1, const float* __restrict__ Whh1,
    const float* __restrict__ bih1, const float* __restrict__ bhh1,
    const int* __restrict__ lens,
    const float* __restrict__ clfw, const float* __restrict__ clfb,
    float* __restrict__ out)
{
  const int b   = blockIdx.x;
  const int tid = threadIdx.x;          // gate row 0..1023

  __shared__ float xb[128];             // pooled[b][t]
  __shared__ float h0[256], c0[256], h1[256], c1[256];
  __shared__ float gbuf[1024];          // raw gate pre-activations

  if (tid < 256) { h0[tid] = 0.f; c0[tid] = 0.f; h1[tid] = 0.f; c1[tid] = 0.f; }
  if (tid < 32)
    ((float4*)xb)[tid] = ((const float4*)(pooled + (size_t)b * 256 * 128))[tid];
  __syncthreads();

  const int len_b = read_len(lens, b);
  const float bias0 = bih0[tid] + bhh0[tid];
  const float bias1 = bih1[tid] + bhh1[tid];
  const float4* wi0 = (const float4*)(Wih0 + (size_t)tid * 128);
  const float4* wh0 = (const float4*)(Whh0 + (size_t)tid * 256);
  const float4* wi1 = (const float4*)(Wih1 + (size_t)tid * 256);
  const float4* wh1 = (const float4*)(Whh1 + (size_t)tid * 256);

  for (int t = 0; t < T_LEN; t++) {
    const bool valid = t < len_b;

    // ---- A: layer-0 gate rows: bias + Wih0[row].x_t + Whh0[row].h0 ----
    float acc = bias0;
    {
      const float4* x4 = (const float4*)xb;
      const float4* h4 = (const float4*)h0;
      #pragma unroll 8
      for (int k = 0; k < 32; k++) {
        float4 w = wi0[k]; float4 v = x4[k];          // v: wave-broadcast LDS
        acc += w.x * v.x + w.y * v.y + w.z * v.z + w.w * v.w;
      }
      #pragma unroll 8
      for (int k = 0; k < 64; k++) {
        float4 w = wh0[k]; float4 v = h4[k];
        acc += w.x * v.x + w.y * v.y + w.z * v.z + w.w * v.w;
      }
    }
    gbuf[tid] = acc;
    __syncthreads();

    // ---- B: cell update layer 0 (thread j<256 owns h0[j],c0[j]) ----
    if (tid < 256) {
      float iv = sigmoidf_(gbuf[tid]);
      float fv = sigmoidf_(gbuf[256 + tid]);
      float gv = tanhf(gbuf[512 + tid]);
      float ov = sigmoidf_(gbuf[768 + tid]);
      float cold = c0[tid], hold = h0[tid];
      float cnew = fv * cold + iv * gv;
      float hnew = ov * tanhf(cnew);
      h0[tid] = valid ? hnew : hold;
      c0[tid] = valid ? cnew : cold;
    }
    __syncthreads();

    // ---- C: layer-1 gate rows + prefetch next x_t ----
    float acc1 = bias1;
    {
      const float4* a4 = (const float4*)h0;
      const float4* h4 = (const float4*)h1;
      #pragma unroll 8
      for (int k = 0; k < 64; k++) {
        float4 w = wi1[k]; float4 v = a4[k];
        acc1 += w.x * v.x + w.y * v.y + w.z * v.z + w.w * v.w;
      }
      #pragma unroll 8
      for (int k = 0; k < 64; k++) {
        float4 w = wh1[k]; float4 v = h4[k];
        acc1 += w.x * v.x + w.y * v.y + w.z * v.z + w.w * v.w;
      }
    }
    if (tid < 32 && t + 1 < T_LEN)   // xb dead after A; safe to overwrite here
      ((float4*)xb)[tid] =
        ((const float4*)(pooled + ((size_t)(b * 256 + t + 1)) * 128))[tid];
    gbuf[tid] = acc1;
    __syncthreads();

    // ---- D: cell update layer 1 ----
    if (tid < 256) {
      float iv = sigmoidf_(gbuf[tid]);
      float fv = sigmoidf_(gbuf[256 + tid]);
      float gv = tanhf(gbuf[512 + tid]);
      float ov = sigmoidf_(gbuf[768 + tid]);
      float cold = c1[tid], hold = h1[tid];
      float cnew = fv * cold + iv * gv;
      float hnew = ov * tanhf(cnew);
      h1[tid] = valid ? hnew : hold;
      c1[tid] = valid ? cnew : cold;
    }
    __syncthreads();
  }

  // classifier: out[b] = h1 . clf_w + clf_b
  if (tid < 256) gbuf[tid] = h1[tid] * clfw[tid];
  __syncthreads();
  for (int s = 128; s > 0; s >>= 1) {
    if (tid < s) gbuf[tid] += gbuf[tid + s];
    __syncthreads();
  }
  if (tid == 0) out[b] = gbuf[0] + clfb[0];
}

// ---------------------------------------------------------------------------
extern "C" void kernel_launch(void* const* d_in, const int* in_sizes, int n_in,
                              void* d_out, int out_size, void* d_ws, size_t ws_size,
                              hipStream_t stream) {
  (void)in_sizes; (void)n_in; (void)out_size; (void)ws_size;
  const float* feat = (const float*)d_in[0];
  const int*   lens = (const int*)d_in[1];
  const float* W1   = (const float*)d_in[2];
  const float* as1  = (const float*)d_in[3];
  const float* ad1  = (const float*)d_in[4];
  const float* b1   = (const float*)d_in[5];
  const float* W2   = (const float*)d_in[6];
  const float* as2  = (const float*)d_in[7];
  const float* ad2  = (const float*)d_in[8];
  const float* b2   = (const float*)d_in[9];
  const float* Wih0 = (const float*)d_in[10];
  const float* Whh0 = (const float*)d_in[11];
  const float* bih0 = (const float*)d_in[12];
  const float* bhh0 = (const float*)d_in[13];
  const float* Wih1 = (const float*)d_in[14];
  const float* Whh1 = (const float*)d_in[15];
  const float* bih1 = (const float*)d_in[16];
  const float* bhh1 = (const float*)d_in[17];
  const float* clfw = (const float*)d_in[18];
  const float* clfb = (const float*)d_in[19];

  float* pooled = (float*)d_ws;   // [8192][128] -> 4 MB ws use

  gat_naive<<<8192, 256, 0, stream>>>(feat, lens, W1, as1, ad1, b1,
                                      W2, as2, ad2, b2, pooled);
  lstm_big<<<32, 1024, 0, stream>>>(pooled, Wih0, bih0, bhh0, Whh0,
                                    Wih1, Whh1, bih1, bhh1,
                                    lens, clfw, clfb, (float*)d_out);
}

// Round 11
// 14467.755 us; speedup vs baseline: 1.8283x; 1.8283x over previous
//
#include <hip/hip_runtime.h>
#include <math.h>

#define A_PL 22
#define F_IN_ 16
#define T_LEN 256

__device__ __forceinline__ float sigmoidf_(float x) { return 1.f / (1.f + __expf(-x)); }

// seq_lengths: int64 or int32. True values in [128,256], never 0 =>
// little-endian int64 has lens32[1]==0.
__device__ __forceinline__ int read_len(const int* __restrict__ lens, int b) {
  return (lens[1] == 0) ? lens[2 * b] : lens[b];
}

// ---------------------------------------------------------------------------
// Kernel 1: NAIVE fused GAT (proven correct in R8 — untouched).
// ---------------------------------------------------------------------------
__global__ __launch_bounds__(256) void gat_naive(
    const float* __restrict__ feat, const int* __restrict__ lens,
    const float* __restrict__ W1, const float* __restrict__ as1,
    const float* __restrict__ ad1, const float* __restrict__ b1,
    const float* __restrict__ W2, const float* __restrict__ as2,
    const float* __restrict__ ad2, const float* __restrict__ b2,
    float* __restrict__ pooled)
{
  const int n = blockIdx.x;
  const int tid = threadIdx.x;
  const int bb = n >> 8;          // batch
  const int tt = n & 255;         // time
  if (tt >= read_len(lens, bb)) { // masked frame: pooled = 0
    if (tid < 128) pooled[(size_t)n * 128 + tid] = 0.f;
    return;
  }

  __shared__ float xs[352];       // x [22][16]
  __shared__ float hbuf[2816];    // per-head h [22][128]; later h2 [22][128]
  __shared__ float x2s[11264];    // GAT1 output [22][512] (relu'd)
  __shared__ float asrc[22], adst[22], alpha[484];

  for (int i = tid; i < 352; i += 256) xs[i] = feat[(size_t)n * 352 + i];
  __syncthreads();

  for (int hd = 0; hd < 4; hd++) {
    for (int i = tid; i < 2816; i += 256) {
      int a = i >> 7, c = i & 127;
      float acc = 0.f;
      for (int f = 0; f < 16; f++) acc += xs[a * 16 + f] * W1[f * 512 + hd * 128 + c];
      hbuf[i] = acc;
    }
    __syncthreads();
    if (tid < 44) {
      int a = tid >> 1;
      const float* av = (tid & 1) ? ad1 : as1;
      float s = 0.f;
      for (int c = 0; c < 128; c++) s += hbuf[a * 128 + c] * av[hd * 128 + c];
      ((tid & 1) ? adst : asrc)[a] = s;
    }
    __syncthreads();
    if (tid < 22) {
      float ev[22], m = -1e30f;
      for (int j = 0; j < 22; j++) {
        float e = adst[tid] + asrc[j];
        e = (e > 0.f) ? e : 0.2f * e;
        ev[j] = e; if (e > m) m = e;
      }
      float s = 0.f;
      for (int j = 0; j < 22; j++) { ev[j] = __expf(ev[j] - m); s += ev[j]; }
      float inv = 1.f / s;
      for (int j = 0; j < 22; j++) alpha[tid * 22 + j] = ev[j] * inv;
    }
    __syncthreads();
    for (int i = tid; i < 2816; i += 256) {
      int a = i >> 7, c = i & 127;
      float acc = 0.f;
      for (int j = 0; j < 22; j++) acc += alpha[a * 22 + j] * hbuf[j * 128 + c];
      x2s[a * 512 + hd * 128 + c] = fmaxf(acc + b1[hd * 128 + c], 0.f);
    }
    __syncthreads();
  }

  for (int i = tid; i < 2816; i += 256) {
    int a = i >> 7, c = i & 127;
    float acc = 0.f;
    for (int k = 0; k < 512; k++) acc += x2s[a * 512 + k] * W2[(size_t)k * 128 + c];
    hbuf[i] = acc;
  }
  __syncthreads();
  if (tid < 44) {
    int a = tid >> 1;
    const float* av = (tid & 1) ? ad2 : as2;
    float s = 0.f;
    for (int c = 0; c < 128; c++) s += hbuf[a * 128 + c] * av[c];
    ((tid & 1) ? adst : asrc)[a] = s;
  }
  __syncthreads();
  if (tid < 22) {
    float ev[22], m = -1e30f;
    for (int j = 0; j < 22; j++) {
      float e = adst[tid] + asrc[j];
      e = (e > 0.f) ? e : 0.2f * e;
      ev[j] = e; if (e > m) m = e;
    }
    float s = 0.f;
    for (int j = 0; j < 22; j++) { ev[j] = __expf(ev[j] - m); s += ev[j]; }
    float inv = 1.f / s;
    for (int j = 0; j < 22; j++) alpha[tid * 22 + j] = ev[j] * inv;
  }
  __syncthreads();
  if (tid < 128) {
    float s = 0.f;
    for (int a = 0; a < 22; a++) {
      float v = b2[tid];
      for (int j = 0; j < 22; j++) v += alpha[a * 22 + j] * hbuf[j * 128 + tid];
      s += fmaxf(v, 0.f);
    }
    pooled[(size_t)n * 128 + tid] = s * (1.f / 22.f);
  }
}

// ---------------------------------------------------------------------------
// Kernel 2: coalesced-stream LSTM. One 1024-thread block per batch (32
// blocks). Gate matvec = wave-per-row split-K: lane l loads W[row][4l..4l+3]
// (one fully-coalesced 1KB wave load — fixes R10's 64-line uncoalesced loads
// = 96us/step), dots against h held in bank-uniform swizzled LDS, 6-step
// __shfl_xor reduce. h/c state in thread-j registers with LDS write-through.
// No grid sync (grid.sync ~30us/call measured in R9).
// Swizzle: logical float j at phys (j&31)+48*(j>>5); lane l reads float4
// index (l&7)+12*(l>>3) -> exactly 8 words/bank (the wave64-b128 floor).
// ---------------------------------------------------------------------------
__global__ __launch_bounds__(1024) void lstm_stream(
    const float* __restrict__ pooled,
    const float* __restrict__ Wih0, const float* __restrict__ bih0,
    const float* __restrict__ bhh0, const float* __restrict__ Whh0,
    const float* __restrict__ Wih1, const float* __restrict__ Whh1,
    const float* __restrict__ bih1, const float* __restrict__ bhh1,
    const int* __restrict__ lens,
    const float* __restrict__ clfw, const float* __restrict__ clfb,
    float* __restrict__ out)
{
  const int b    = blockIdx.x;
  const int tid  = threadIdx.x;
  const int wave = tid >> 6;
  const int lane = tid & 63;
  const int rbase = wave * 64;                   // this wave's 64 gate rows
  const int f4h  = (lane & 7) + 12 * (lane >> 3); // swizzled float4 read idx

  __shared__ float h0s[368], h1s[368], xbs[176]; // swizzled h0/h1/x
  __shared__ float gbuf[1024];                   // gate pre-activations

  for (int i = tid; i < 368; i += 1024) { h0s[i] = 0.f; h1s[i] = 0.f; }
  if (tid < 32) {   // x_0
    float4 v = ((const float4*)(pooled + (size_t)b * 256 * 128))[tid];
    ((float4*)xbs)[(tid & 7) + 12 * (tid >> 3)] = v;
  }

  const int len_b = read_len(lens, b);

  // per-thread (j = tid < 256) cell state + biases + swizzled store index
  float h0r = 0.f, c0r = 0.f, h1r = 0.f, c1r = 0.f;
  float bA0 = 0.f, bA1 = 0.f, bA2 = 0.f, bA3 = 0.f;
  float bB0 = 0.f, bB1 = 0.f, bB2 = 0.f, bB3 = 0.f;
  const int physj = (tid & 31) + 48 * (tid >> 5);
  if (tid < 256) {
    bA0 = bih0[tid]       + bhh0[tid];
    bA1 = bih0[256 + tid] + bhh0[256 + tid];
    bA2 = bih0[512 + tid] + bhh0[512 + tid];
    bA3 = bih0[768 + tid] + bhh0[768 + tid];
    bB0 = bih1[tid]       + bhh1[tid];
    bB1 = bih1[256 + tid] + bhh1[256 + tid];
    bB2 = bih1[512 + tid] + bhh1[512 + tid];
    bB3 = bih1[768 + tid] + bhh1[768 + tid];
  }
  float4 xpre = make_float4(0.f, 0.f, 0.f, 0.f);
  __syncthreads();

  for (int t = 0; t < T_LEN; t++) {
    const bool valid = t < len_b;

    // ---- phase A: layer-0 gate rows (all 16 waves x 64 rows) ----
    {
      float4 hv = ((const float4*)h0s)[f4h];
      float4 xv = make_float4(0.f, 0.f, 0.f, 0.f);
      if (lane < 32) xv = ((const float4*)xbs)[f4h];
      #pragma unroll 4
      for (int r = 0; r < 64; ++r) {
        int row = rbase + r;
        float4 wh = *(const float4*)(Whh0 + ((size_t)row << 8) + (lane << 2));
        float acc = wh.x * hv.x + wh.y * hv.y + wh.z * hv.z + wh.w * hv.w;
        if (lane < 32) {
          float4 wi = *(const float4*)(Wih0 + ((size_t)row << 7) + (lane << 2));
          acc += wi.x * xv.x + wi.y * xv.y + wi.z * xv.z + wi.w * xv.w;
        }
        #pragma unroll
        for (int off = 32; off > 0; off >>= 1) acc += __shfl_xor(acc, off);
        if (lane == 0) gbuf[row] = acc;
      }
    }
    __syncthreads();

    // ---- phase B: layer-0 cell update (j<256); x prefetch issue ----
    if (tid < 256) {
      float iv = sigmoidf_(gbuf[tid]       + bA0);
      float fv = sigmoidf_(gbuf[256 + tid] + bA1);
      float gv = tanhf(gbuf[512 + tid]     + bA2);
      float ov = sigmoidf_(gbuf[768 + tid] + bA3);
      float cnew = fv * c0r + iv * gv;
      float hnew = ov * tanhf(cnew);
      if (valid) { c0r = cnew; h0r = hnew; }
      h0s[physj] = h0r;
    } else if (tid < 288 && t + 1 < T_LEN) {
      xpre = ((const float4*)(pooled + (((size_t)(b * 256 + t + 1)) << 7)))[tid - 256];
    }
    __syncthreads();

    // ---- phase C: layer-1 gate rows ----
    {
      float4 h0v = ((const float4*)h0s)[f4h];
      float4 h1v = ((const float4*)h1s)[f4h];
      #pragma unroll 4
      for (int r = 0; r < 64; ++r) {
        int row = rbase + r;
        float4 wi = *(const float4*)(Wih1 + ((size_t)row << 8) + (lane << 2));
        float4 wh = *(const float4*)(Whh1 + ((size_t)row << 8) + (lane << 2));
        float acc = wi.x * h0v.x + wi.y * h0v.y + wi.z * h0v.z + wi.w * h0v.w
                  + wh.x * h1v.x + wh.y * h1v.y + wh.z * h1v.z + wh.w * h1v.w;
        #pragma unroll
        for (int off = 32; off > 0; off >>= 1) acc += __shfl_xor(acc, off);
        if (lane == 0) gbuf[row] = acc;
      }
    }
    __syncthreads();

    // ---- phase D: layer-1 cell update; commit prefetched x ----
    if (tid < 256) {
      float iv = sigmoidf_(gbuf[tid]       + bB0);
      float fv = sigmoidf_(gbuf[256 + tid] + bB1);
      float gv = tanhf(gbuf[512 + tid]     + bB2);
      float ov = sigmoidf_(gbuf[768 + tid] + bB3);
      float cnew = fv * c1r + iv * gv;
      float hnew = ov * tanhf(cnew);
      if (valid) { c1r = cnew; h1r = hnew; }
      h1s[physj] = h1r;
    } else if (tid < 288 && t + 1 < T_LEN) {
      int i = tid - 256;
      ((float4*)xbs)[(i & 7) + 12 * (i >> 3)] = xpre;
    }
    __syncthreads();
  }

  // classifier: out[b] = h1 . clf_w + clf_b  (h1r lives in thread j's regs)
  if (tid < 256) gbuf[tid] = h1r * clfw[tid];
  __syncthreads();
  for (int s = 128; s > 0; s >>= 1) {
    if (tid < s) gbuf[tid] += gbuf[tid + s];
    __syncthreads();
  }
  if (tid == 0) out[b] = gbuf[0] + clfb[0];
}

// ---------------------------------------------------------------------------
extern "C" void kernel_launch(void* const* d_in, const int* in_sizes, int n_in,
                              void* d_out, int out_size, void* d_ws, size_t ws_size,
                              hipStream_t stream) {
  (void)in_sizes; (void)n_in; (void)out_size; (void)ws_size;
  const float* feat = (const float*)d_in[0];
  const int*   lens = (const int*)d_in[1];
  const float* W1   = (const float*)d_in[2];
  const float* as1  = (const float*)d_in[3];
  const float* ad1  = (const float*)d_in[4];
  const float* b1   = (const float*)d_in[5];
  const float* W2   = (const float*)d_in[6];
  const float* as2  = (const float*)d_in[7];
  const float* ad2  = (const float*)d_in[8];
  const float* b2   = (const float*)d_in[9];
  const float* Wih0 = (const float*)d_in[10];
  const float* Whh0 = (const float*)d_in[11];
  const float* bih0 = (const float*)d_in[12];
  const float* bhh0 = (const float*)d_in[13];
  const float* Wih1 = (const float*)d_in[14];
  const float* Whh1 = (const float*)d_in[15];
  const float* bih1 = (const float*)d_in[16];
  const float* bhh1 = (const float*)d_in[17];
  const float* clfw = (const float*)d_in[18];
  const float* clfb = (const float*)d_in[19];

  float* pooled = (float*)d_ws;   // [8192][128] -> 4 MB ws use

  gat_naive<<<8192, 256, 0, stream>>>(feat, lens, W1, as1, ad1, b1,
                                      W2, as2, ad2, b2, pooled);
  lstm_stream<<<32, 1024, 0, stream>>>(pooled, Wih0, bih0, bhh0, Whh0,
                                       Wih1, Whh1, bih1, bhh1,
                                       lens, clfw, clfb, (float*)d_out);
}